// Round 7
// baseline (53.256 us; speedup 1.0000x reference)
//
#include <hip/hip_runtime.h>
#include <hip/hip_bf16.h>
#include <stdint.h>

// Problem constants
#define BB 64      // batch
#define LL 256     // x seq len
#define TT 64      // y seq len
#define DD 512     // input dim
#define EE 200     // embed dim
#define EP 208     // embed dim padded to 13*16 (32x32x16 MFMA K-granularity)
#define NKK 13     // K-steps in pair kernel (EP/16)
#define NROWS_X 16384   // 64*256
// Fragment-chunk layout: 1 chunk = 32 rows x 16 e = 64 lanes x 16 B = 1024 B.
// lane l holds row (l&31), e_local (l>>5)*8 .. +8, at shorts chunk*512 + l*8.
// Unified pT: chunk index = (global_row >> 5)*13 + n (x rows first, then y).
// ypT starts at chunk 6656 ( = (16384>>5)*13 ).
#define YCH_PER_J (2 * NKK * 64)   // 16B-units per j slice = 1664
#define BSTRIDE 264                // proj bounce row stride in shorts

typedef __attribute__((ext_vector_type(8))) short short8;
typedef __attribute__((ext_vector_type(4))) float floatx4;
typedef __attribute__((ext_vector_type(16))) float floatx16;

__device__ __forceinline__ short f2bf(float f) {
  uint32_t u = __builtin_bit_cast(uint32_t, f);
  u = (u + 0x7fffu + ((u >> 16) & 1u)) >> 16;  // RNE
  return (short)u;
}

// Pack two f32 (truncating to bf16) into one u32 with a single v_perm.
__device__ __forceinline__ uint32_t pack2(float lo, float hi) {
  return __builtin_amdgcn_perm(__builtin_bit_cast(uint32_t, hi),
                               __builtin_bit_cast(uint32_t, lo), 0x07060302u);
}

typedef const __attribute__((address_space(1))) uint32_t gu32_t;
typedef __attribute__((address_space(3))) uint32_t lu32_t;
__device__ __forceinline__ void glds16(const void* g, void* l) {
  __builtin_amdgcn_global_load_lds((gu32_t*)g, (lu32_t*)l, 16, 0, 0);
}

// counted-vmcnt barrier: wait until only the newest N vmem ops remain, then barrier.
#define VMCNT_BARRIER(N) asm volatile("s_waitcnt vmcnt(" #N ")\n\ts_barrier" ::: "memory")

// ---------------- Kernel 0: W (200x512 f32) -> Wb (208x512 bf16, zero-padded), x8 vec
__global__ void wcvt_kernel(const float* __restrict__ W, short* __restrict__ Wb) {
  const int t = blockIdx.x * 256 + threadIdx.x;   // 0 .. 13311
  const int base = t * 8;
  const int e = base >> 9;
  union { short8 s8; uint32_t u[4]; } o;
  if (e < EE) {
    const floatx4 f0 = *(const floatx4*)(W + base);
    const floatx4 f1 = *(const floatx4*)(W + base + 4);
    o.u[0] = pack2(f0.x, f0.y); o.u[1] = pack2(f0.z, f0.w);
    o.u[2] = pack2(f1.x, f1.y); o.u[3] = pack2(f1.z, f1.w);
  } else {
    o.u[0] = o.u[1] = o.u[2] = o.u[3] = 0u;
  }
  *(short8*)(Wb + base) = o.s8;
}

// ---------------- Kernel 1: projection GEMM -> fragment-layout pT
// M=20480 rows (x then y), N=208, K=512. 256 thr = 4 waves, wave = 16 rows x 208 E.
// BM=64, BK=32, TRIPLE-buffered global_load_lds with counted vmcnt (depth-2 pipeline).
// Stage = 6 glds/thread uniform (A 2 + B 4, B rows padded to 256 via clamp).
__global__ __launch_bounds__(256, 2) void proj_kernel(const float* __restrict__ x,
                                                      const float* __restrict__ y,
                                                      const short* __restrict__ Wb,
                                                      const float* __restrict__ bias,
                                                      short* __restrict__ pT) {
  __shared__ __align__(16) char smem[73728];
  float* ldsA = (float*)smem;               // [3][64*32]  f32   24,576 B
  short* ldsB = (short*)(smem + 24576);     // [3][256*32] bf16  49,152 B
  short* bounce = (short*)smem;             // [64][BSTRIDE] 33,792 B (after loop)

  const int tid  = threadIdx.x;
  const int lane = tid & 63;
  const int wid  = tid >> 6;
  const int r16   = lane & 15;
  const int khalf = lane >> 4;        // 0..3

  const int row0 = blockIdx.x * 64;
  const float* srcbase = (row0 < NROWS_X) ? (x + (size_t)row0 * DD)
                                          : (y + (size_t)(row0 - NROWS_X) * DD);

  floatx4 acc[NKK];
#pragma unroll
  for (int n = 0; n < NKK; n++) acc[n] = (floatx4){0.f, 0.f, 0.f, 0.f};

  // Stage K-step ks into buffer buf (exactly 6 glds per thread, wave-uniform).
  // ldsA[r][c16] <- x[r][ks*32 + (c^(r&7))*4 ..+4)
  // ldsB[r][c16] <- Wb[min(r,207)][ks*32 + (c^(r&3))*8 ..+8)   (rows 208..255 never read)
  auto stage = [&](int buf, int ks) {
#pragma unroll
    for (int it = 0; it < 2; it++) {
      const int p = it * 256 + tid;
      const int r = p >> 3, c = p & 7;
      glds16(srcbase + (size_t)r * DD + ks * 32 + ((c ^ (r & 7)) << 2),
             &ldsA[buf * 2048 + p * 4]);
    }
#pragma unroll
    for (int it = 0; it < 4; it++) {
      const int p = it * 256 + tid;
      const int r = p >> 2, c = p & 3;
      const int sr = (r < EP) ? r : (EP - 1);
      glds16(Wb + (size_t)sr * DD + ks * 32 + ((c ^ (r & 3)) << 3),
             &ldsB[buf * 8192 + p * 8]);
    }
  };

  auto compute = [&](int s) {
    const int buf = s % 3;
    const int r = wid * 16 + r16;
    const int c0 = (2 * khalf) ^ (r & 7);
    const int c1 = (2 * khalf + 1) ^ (r & 7);
    const floatx4 f0 = *(const floatx4*)&ldsA[buf * 2048 + r * 32 + c0 * 4];
    const floatx4 f1 = *(const floatx4*)&ldsA[buf * 2048 + r * 32 + c1 * 4];
    union { short8 s8; uint32_t u[4]; } af;
    af.u[0] = pack2(f0.x, f0.y);
    af.u[1] = pack2(f0.z, f0.w);
    af.u[2] = pack2(f1.x, f1.y);
    af.u[3] = pack2(f1.z, f1.w);
#pragma unroll
    for (int n = 0; n < NKK; n++) {
      const int erow = n * 16 + r16;
      const short8 bfrag = *(const short8*)&ldsB[buf * 8192 + erow * 32 + ((khalf ^ (erow & 3)) << 3)];
      acc[n] = __builtin_amdgcn_mfma_f32_16x16x32_bf16(af.s8, bfrag, acc[n], 0, 0, 0);
    }
  };

  stage(0, 0);
  stage(1, 1);

  for (int s = 0; s < 15; s++) {
    VMCNT_BARRIER(6);                 // stage(s) complete block-wide; stage(s+1) in flight
    if (s + 2 < 16) stage((s + 2) % 3, s + 2);  // writes buf != s%3, != (s+1)%3; readers of
                                                // that buf finished before this barrier
    compute(s);
  }
  VMCNT_BARRIER(0);                   // drain stage(15)
  compute(15);

  __syncthreads();   // all LDS reads done; safe to reuse smem as bounce

  // Epilogue 1: bias + f2bf -> bounce[lr][e]  (pad e>=EE stores 0: acc 0 + bv 0)
#pragma unroll
  for (int n = 0; n < NKK; n++) {
    const int e = n * 16 + r16;
    const float bv = (e < EE) ? bias[e] : 0.0f;
#pragma unroll
    for (int rr = 0; rr < 4; rr++) {
      const int lr = wid * 16 + khalf * 4 + rr;
      bounce[lr * BSTRIDE + e] = f2bf(acc[n][rr] + bv);
    }
  }
  __syncthreads();

  // Epilogue 2: read fragment pieces (16B) and store coalesced into chunk layout.
  const int rowblk0 = row0 >> 5;
  for (int c = tid; c < 1664; c += 256) {
    const int q  = c >> 6;
    const int mt = (q >= 13) ? 1 : 0;
    const int n  = q - mt * 13;
    const int l  = c & 63;
    const int lr = mt * 32 + (l & 31);
    const short8 piece = *(const short8*)&bounce[lr * BSTRIDE + n * 16 + (l >> 5) * 8];
    *(short8*)&pT[((size_t)((rowblk0 + mt) * 13 + n)) * 512 + l * 8] = piece;
  }
}

// ---------------- Kernel 2: pair kernel, Bi=4 x Bj=4, grid 256 = 1 block/CU,
// 1024 thr = 16 waves (4/SIMD): wave = (wq = L-tile-pair 0..3) x (jw = j 0..3).
// acc = 2m x 2nt x f32x16 = 64 VGPR -> fits 128-cap for 4 waves/SIMD.
// XCD-grouped swizzle: blocks sharing igrp land on one XCD (A set 1.66MB < 4MB L2).
__global__ __launch_bounds__(1024, 4) void pair_kernel(const short* __restrict__ xpT,
                                                       const short* __restrict__ ypT,
                                                       float* __restrict__ S) {
  __shared__ __align__(16) char ldsbuf[106496 + 16384];
  short* ylds = (short*)ldsbuf;                  // 104 chunks: (jl*2+nt)*13+kk
  float* red  = (float*)(ldsbuf + 106496);       // [wq][ii][jl][64 t]

  const int tid  = threadIdx.x;
  const int lane = tid & 63;
  const int wid  = tid >> 6;         // 0..15
  const int wq   = wid & 3;          // L-tile pair
  const int jw   = wid >> 2;         // j within block
  const int bid  = blockIdx.x;
  const int igrp = ((bid & 7) << 1) | ((bid >> 3) & 1);  // 0..15, fixed per XCD-pair
  const int jgrp = bid >> 4;                              // 0..15
  const int ibase = igrp * 4;
  const int j0    = jgrp * 4;

  // Stage 4 j-slices: 4*1664 = 6656 16B-units; 1024 thr -> 6 full + half iter.
  {
    const short* src = ypT + (size_t)j0 * YCH_PER_J * 8;
    for (int c = tid; c < 4 * YCH_PER_J; c += 1024) {
      glds16(src + (size_t)c * 8, ldsbuf + c * 16);
    }
  }
  __syncthreads();

  for (int ii = 0; ii < 4; ii++) {
    const int i = ibase + ii;

    floatx16 acc[2][2];              // [m][nt]
#pragma unroll
    for (int m = 0; m < 2; m++)
#pragma unroll
      for (int nt = 0; nt < 2; nt++)
#pragma unroll
        for (int r = 0; r < 16; r++) acc[m][nt][r] = 0.f;

    const short* a0base = xpT + ((size_t)((i * 8 + wq * 2 + 0) * NKK) * 512) + lane * 8;
    const short* a1base = xpT + ((size_t)((i * 8 + wq * 2 + 1) * NKK) * 512) + lane * 8;

#pragma unroll
    for (int kk = 0; kk < NKK; kk++) {
      const short8 a0 = *(const short8*)(a0base + kk * 512);
      const short8 a1 = *(const short8*)(a1base + kk * 512);
#pragma unroll
      for (int nt = 0; nt < 2; nt++) {
        const short8 bf = *(const short8*)(ylds + ((size_t)((jw * 2 + nt) * NKK + kk)) * 512 + lane * 8);
        acc[0][nt] = __builtin_amdgcn_mfma_f32_32x32x16_bf16(a0, bf, acc[0][nt], 0, 0, 0);
        acc[1][nt] = __builtin_amdgcn_mfma_f32_32x32x16_bf16(a1, bf, acc[1][nt], 0, 0, 0);
      }
    }

    // Max over this wave's 64 L-rows per column t (C layout: col = lane&31).
#pragma unroll
    for (int nt = 0; nt < 2; nt++) {
      float v = acc[0][nt][0];
#pragma unroll
      for (int m = 0; m < 2; m++)
#pragma unroll
        for (int r = 0; r < 16; r++) v = fmaxf(v, acc[m][nt][r]);
      v = fmaxf(v, __shfl_xor(v, 32, 64));
      if (lane < 32)
        red[((wq * 4 + ii) * 4 + jw) * 64 + nt * 32 + lane] = v;
    }
  }
  __syncthreads();

  // Final: 16 (ii,jl) combos x 64 t; wave wid takes combo wid.
  {
    const int ii = wid >> 2;
    const int jl = wid & 3;
    const int t  = lane;
    float v = red[((0 * 4 + ii) * 4 + jl) * 64 + t];
    v = fmaxf(v, red[((1 * 4 + ii) * 4 + jl) * 64 + t]);
    v = fmaxf(v, red[((2 * 4 + ii) * 4 + jl) * 64 + t]);
    v = fmaxf(v, red[((3 * 4 + ii) * 4 + jl) * 64 + t]);
    v += __shfl_xor(v, 1, 64);
    v += __shfl_xor(v, 2, 64);
    v += __shfl_xor(v, 4, 64);
    v += __shfl_xor(v, 8, 64);
    v += __shfl_xor(v, 16, 64);
    v += __shfl_xor(v, 32, 64);
    if (t == 0) S[(ibase + ii) * BB + j0 + jl] = v * (1.0f / 64.0f);
  }
}

extern "C" void kernel_launch(void* const* d_in, const int* in_sizes, int n_in,
                              void* d_out, int out_size, void* d_ws, size_t ws_size,
                              hipStream_t stream) {
  const float* x = (const float*)d_in[0];   // 64*256*512
  const float* y = (const float*)d_in[1];   // 64*64*512
  const float* W = (const float*)d_in[2];   // 200*512
  const float* b = (const float*)d_in[3];   // 200
  float* S = (float*)d_out;                 // 64*64

  char* ws = (char*)d_ws;
  short* Wb = (short*)ws;                   // 208*512*2 = 212,992 B
  short* pT = (short*)(ws + 262144);        // 8320 chunks * 1024 B = 8,519,680 B
  short* ypT = pT + (size_t)6656 * 512;     // y starts at chunk 6656

  wcvt_kernel<<<52, 256, 0, stream>>>(W, Wb);
  proj_kernel<<<320, 256, 0, stream>>>(x, y, Wb, b, pT);
  pair_kernel<<<256, 1024, 0, stream>>>(pT, ypT, S);
}